// Round 1
// baseline (1675.070 us; speedup 1.0000x reference)
//
#include <hip/hip_runtime.h>

#define FD 128            // feature dim
#define WAVE 64

// ---------------------------------------------------------------------------
// CSR build kernels
// ---------------------------------------------------------------------------

__global__ __launch_bounds__(256) void hist_kernel(const int* __restrict__ dst,
                                                   int* __restrict__ deg, int E) {
    int e = blockIdx.x * 256 + threadIdx.x;
    if (e < E) atomicAdd(&deg[dst[e]], 1);
}

// Single-block exclusive scan over deg[0..n): writes row_ptr, cursor(=row_ptr copy),
// rdeg = 1/max(deg,1).
__global__ __launch_bounds__(1024) void scan_kernel(const int* __restrict__ deg,
                                                    int* __restrict__ row_ptr,
                                                    int* __restrict__ cursor,
                                                    float* __restrict__ rdeg, int n) {
    __shared__ int ps[1024];
    int tid = threadIdx.x;
    int chunk = (n + 1023) >> 10;
    int start = tid * chunk;
    int end = start + chunk; if (end > n) end = n;
    int s = 0;
    for (int i = start; i < end; ++i) s += deg[i];
    ps[tid] = s;
    __syncthreads();
    for (int off = 1; off < 1024; off <<= 1) {
        int v = (tid >= off) ? ps[tid - off] : 0;
        __syncthreads();
        ps[tid] += v;
        __syncthreads();
    }
    int base = ps[tid] - s;   // exclusive prefix of this thread's chunk
    for (int i = start; i < end; ++i) {
        int d = deg[i];
        row_ptr[i] = base;
        cursor[i] = base;
        rdeg[i] = 1.0f / (float)(d > 1 ? d : 1);
        base += d;
    }
}

__global__ __launch_bounds__(256) void fill_kernel(const int* __restrict__ src,
                                                   const int* __restrict__ dst,
                                                   int* __restrict__ cursor,
                                                   int* __restrict__ csr, int E) {
    int e = blockIdx.x * 256 + threadIdx.x;
    if (e < E) {
        int p = atomicAdd(&cursor[dst[e]], 1);
        csr[p] = src[e];
    }
}

// ---------------------------------------------------------------------------
// Mean aggregation: one wave (64 lanes) per dst node, float2 per lane (128 cols).
// ---------------------------------------------------------------------------
__global__ __launch_bounds__(256) void agg_kernel(const float* __restrict__ h,
                                                  const int* __restrict__ row_ptr,
                                                  const int* __restrict__ deg,
                                                  const float* __restrict__ rdeg,
                                                  const int* __restrict__ csr,
                                                  float* __restrict__ out, int n) {
    int node = (blockIdx.x * 256 + threadIdx.x) >> 6;
    int lane = threadIdx.x & 63;
    if (node >= n) return;
    int start = row_ptr[node];
    int d = deg[node];
    const float2* hp = (const float2*)h;
    float ax = 0.f, ay = 0.f;
    int i = 0;
    for (; i + 4 <= d; i += 4) {
        int s0 = csr[start + i + 0];
        int s1 = csr[start + i + 1];
        int s2 = csr[start + i + 2];
        int s3 = csr[start + i + 3];
        float2 v0 = hp[s0 * 64 + lane];
        float2 v1 = hp[s1 * 64 + lane];
        float2 v2 = hp[s2 * 64 + lane];
        float2 v3 = hp[s3 * 64 + lane];
        ax += v0.x; ay += v0.y;
        ax += v1.x; ay += v1.y;
        ax += v2.x; ay += v2.y;
        ax += v3.x; ay += v3.y;
    }
    for (; i < d; ++i) {
        int s0 = csr[start + i];
        float2 v0 = hp[s0 * 64 + lane];
        ax += v0.x; ay += v0.y;
    }
    float r = rdeg[node];
    float2 o; o.x = ax * r; o.y = ay * r;
    ((float2*)out)[node * 64 + lane] = o;
}

// ---------------------------------------------------------------------------
// Fused GEMM: out[m,:] = A[m,:] @ Wl^T + H[m,:] @ Wr^T + b  (+optional ReLU)
// A is the aggregation buffer; out may alias A (row-local in-place).
// Block: 64 rows x 128 cols, 256 threads, each thread 8 rows x 4 cols.
// LDS tiles stored transposed ([k][row] / [k][col]) so compute reads are
// b128 (W, conflict-free 16B-stride) and broadcast (A).
// ---------------------------------------------------------------------------
__global__ __launch_bounds__(256) void gemm_kernel(const float* A, const float* H,
                                                   const float* __restrict__ Wl,
                                                   const float* __restrict__ Wr,
                                                   const float* __restrict__ bias,
                                                   float* out, int n, int do_relu) {
    __shared__ float Alds[32][64];
    __shared__ float Wlds[32][128];
    int tid = threadIdx.x;
    int block_row = blockIdx.x * 64;
    int tc = tid & 31;        // col group: cols tc*4 .. tc*4+3
    int tr = tid >> 5;        // row group: rows tr*8 .. tr*8+7

    float acc[8][4];
#pragma unroll
    for (int r = 0; r < 8; ++r)
#pragma unroll
        for (int c = 0; c < 4; ++c) acc[r][c] = 0.f;

    for (int ch = 0; ch < 8; ++ch) {
        const float* srcm = (ch < 4) ? A : H;
        const float* W    = (ch < 4) ? Wl : Wr;
        int koff = (ch & 3) * 32;

        // stage A tile (64 rows x 32 k) transposed -> Alds[k][row]
#pragma unroll
        for (int t = 0; t < 2; ++t) {
            int f4 = tid + t * 256;
            int row = f4 >> 3;
            int k4 = (f4 & 7) * 4;
            int grow = block_row + row;
            if (grow >= n) grow = n - 1;
            const float4 v = *(const float4*)(srcm + (size_t)grow * FD + koff + k4);
            Alds[k4 + 0][row] = v.x;
            Alds[k4 + 1][row] = v.y;
            Alds[k4 + 2][row] = v.z;
            Alds[k4 + 3][row] = v.w;
        }
        // stage W tile (128 j x 32 k) transposed -> Wlds[k][j]
#pragma unroll
        for (int t = 0; t < 4; ++t) {
            int f4 = tid + t * 256;
            int j = f4 >> 3;
            int k4 = (f4 & 7) * 4;
            const float4 v = *(const float4*)(W + j * FD + koff + k4);
            Wlds[k4 + 0][j] = v.x;
            Wlds[k4 + 1][j] = v.y;
            Wlds[k4 + 2][j] = v.z;
            Wlds[k4 + 3][j] = v.w;
        }
        __syncthreads();

#pragma unroll
        for (int k = 0; k < 32; ++k) {
            float4 w  = *(const float4*)&Wlds[k][tc * 4];
            float4 a0 = *(const float4*)&Alds[k][tr * 8];
            float4 a1 = *(const float4*)&Alds[k][tr * 8 + 4];
            float ar[8] = {a0.x, a0.y, a0.z, a0.w, a1.x, a1.y, a1.z, a1.w};
#pragma unroll
            for (int r = 0; r < 8; ++r) {
                acc[r][0] += ar[r] * w.x;
                acc[r][1] += ar[r] * w.y;
                acc[r][2] += ar[r] * w.z;
                acc[r][3] += ar[r] * w.w;
            }
        }
        __syncthreads();
    }

    float4 b4 = *(const float4*)(bias + tc * 4);
#pragma unroll
    for (int r = 0; r < 8; ++r) {
        int grow = block_row + tr * 8 + r;
        if (grow < n) {
            float4 o;
            o.x = acc[r][0] + b4.x;
            o.y = acc[r][1] + b4.y;
            o.z = acc[r][2] + b4.z;
            o.w = acc[r][3] + b4.w;
            if (do_relu) {
                o.x = o.x > 0.f ? o.x : 0.f;
                o.y = o.y > 0.f ? o.y : 0.f;
                o.z = o.z > 0.f ? o.z : 0.f;
                o.w = o.w > 0.f ? o.w : 0.f;
            }
            *(float4*)(out + (size_t)grow * FD + tc * 4) = o;
        }
    }
}

// ---------------------------------------------------------------------------
extern "C" void kernel_launch(void* const* d_in, const int* in_sizes, int n_in,
                              void* d_out, int out_size, void* d_ws, size_t ws_size,
                              hipStream_t stream) {
    const float* x   = (const float*)d_in[0];
    const int*   ei  = (const int*)d_in[1];
    const float* W1l = (const float*)d_in[2];
    const float* W1r = (const float*)d_in[3];
    const float* W2l = (const float*)d_in[4];
    const float* W2r = (const float*)d_in[5];
    const float* W3l = (const float*)d_in[6];
    const float* W3r = (const float*)d_in[7];
    const float* b1  = (const float*)d_in[8];
    const float* b2  = (const float*)d_in[9];
    const float* b3  = (const float*)d_in[10];
    float* out = (float*)d_out;

    int N = in_sizes[0] / FD;
    int E = in_sizes[1] / 2;
    const int* src = ei;
    const int* dst = ei + E;

    char* ws = (char*)d_ws;
    size_t off = 0;
    auto alloc = [&](size_t bytes) -> void* {
        void* p = ws + off;
        off += (bytes + 255) & ~(size_t)255;
        return p;
    };
    int*   deg     = (int*)alloc((size_t)N * 4);
    int*   row_ptr = (int*)alloc((size_t)N * 4);
    int*   cursor  = (int*)alloc((size_t)N * 4);
    float* rdeg    = (float*)alloc((size_t)N * 4);
    int*   csr     = (int*)alloc((size_t)E * 4);
    float* bufA    = (float*)alloc((size_t)N * FD * 4);
    float* bufB    = (float*)alloc((size_t)N * FD * 4);

    // ---- CSR build (once; reused by all 3 layers) ----
    hipMemsetAsync(deg, 0, (size_t)N * 4, stream);
    hist_kernel<<<(E + 255) / 256, 256, 0, stream>>>(dst, deg, E);
    scan_kernel<<<1, 1024, 0, stream>>>(deg, row_ptr, cursor, rdeg, N);
    fill_kernel<<<(E + 255) / 256, 256, 0, stream>>>(src, dst, cursor, csr, E);

    int aggGrid  = (N + 3) / 4;     // 4 waves (nodes) per 256-thread block
    int gemmGrid = (N + 63) / 64;

    // layer 1: h1 = relu(mean(x) @ W1l^T + b1 + x @ W1r^T)   -> bufA
    agg_kernel<<<aggGrid, 256, 0, stream>>>(x, row_ptr, deg, rdeg, csr, bufA, N);
    gemm_kernel<<<gemmGrid, 256, 0, stream>>>(bufA, x, W1l, W1r, b1, bufA, N, 1);
    // layer 2: h2 -> bufB
    agg_kernel<<<aggGrid, 256, 0, stream>>>(bufA, row_ptr, deg, rdeg, csr, bufB, N);
    gemm_kernel<<<gemmGrid, 256, 0, stream>>>(bufB, bufA, W2l, W2r, b2, bufB, N, 1);
    // layer 3: out (no relu), agg into d_out then in-place GEMM
    agg_kernel<<<aggGrid, 256, 0, stream>>>(bufB, row_ptr, deg, rdeg, csr, out, N);
    gemm_kernel<<<gemmGrid, 256, 0, stream>>>(out, bufB, W3l, W3r, b3, out, N, 0);
}

// Round 2
// 1186.466 us; speedup vs baseline: 1.4118x; 1.4118x over previous
//
#include <hip/hip_runtime.h>

#define FD 128            // feature dim
#define NBLK 256          // blocks for bucket hist/scatter (must match grid)
#define BSHIFT 9          // bucket = dst >> 9  (512 nodes per bucket)
#define BNODES 512

// ---------------------------------------------------------------------------
// Two-level counting sort CSR build
// ---------------------------------------------------------------------------

// K1: per-(block,bucket) histogram via LDS. counts[b*NBLK + blk]
__global__ __launch_bounds__(256) void bucket_hist(const int* __restrict__ dst,
                                                   int* __restrict__ counts,
                                                   int E, int B) {
    __shared__ int h[256];
    int t = threadIdx.x;
    h[t] = 0;
    __syncthreads();
    for (int e = blockIdx.x * 256 + t; e < E; e += NBLK * 256)
        atomicAdd(&h[dst[e] >> BSHIFT], 1);
    __syncthreads();
    for (int b = t; b < B; b += 256)
        counts[b * NBLK + blockIdx.x] = h[b];
}

// ---- generic 3-phase exclusive scan (int) ----
__global__ __launch_bounds__(256) void scan_sums(const int* __restrict__ in,
                                                 int* __restrict__ sums, int n) {
    __shared__ int red[256];
    int t = threadIdx.x;
    int i = blockIdx.x * 256 + t;
    red[t] = (i < n) ? in[i] : 0;
    __syncthreads();
    for (int off = 128; off > 0; off >>= 1) {
        if (t < off) red[t] += red[t + off];
        __syncthreads();
    }
    if (t == 0) sums[blockIdx.x] = red[0];
}

// single block, exclusive scan of sums[0..m), m <= 1024
__global__ __launch_bounds__(1024) void scan_top(int* __restrict__ sums, int m) {
    __shared__ int s[1024];
    int t = threadIdx.x;
    int v = (t < m) ? sums[t] : 0;
    s[t] = v;
    __syncthreads();
    for (int off = 1; off < 1024; off <<= 1) {
        int u = (t >= off) ? s[t - off] : 0;
        __syncthreads();
        s[t] += u;
        __syncthreads();
    }
    if (t < m) sums[t] = s[t] - v;   // exclusive
}

__global__ __launch_bounds__(256) void scan_apply(const int* __restrict__ in,
                                                  const int* __restrict__ sums,
                                                  int* __restrict__ out, int n) {
    __shared__ int s[256];
    int t = threadIdx.x;
    int i = blockIdx.x * 256 + t;
    int v = (i < n) ? in[i] : 0;
    s[t] = v;
    __syncthreads();
    for (int off = 1; off < 256; off <<= 1) {
        int u = (t >= off) ? s[t - off] : 0;
        __syncthreads();
        s[t] += u;
        __syncthreads();
    }
    if (i < n) out[i] = sums[blockIdx.x] + s[t] - v;   // exclusive
}

// K3: scatter edges into bucket-major order. Per-(bucket,block) runs are
// contiguous -> sequential 8B writes, ~1.2x amplification instead of 16x.
__global__ __launch_bounds__(256) void bucket_scatter(const int* __restrict__ src,
                                                      const int* __restrict__ dst,
                                                      const int* __restrict__ coff,
                                                      int2* __restrict__ sorted,
                                                      int E, int B) {
    __shared__ int cur[256];
    int t = threadIdx.x;
    for (int b = t; b < B; b += 256) cur[b] = coff[b * NBLK + blockIdx.x];
    __syncthreads();
    for (int e = blockIdx.x * 256 + t; e < E; e += NBLK * 256) {
        int d = dst[e];
        int p = atomicAdd(&cur[d >> BSHIFT], 1);
        sorted[p] = make_int2(src[e], d);
    }
}

// K4: per-node degree from bucket-sorted edges (LDS counters, coalesced reads).
__global__ __launch_bounds__(256) void bucket_deg(const int2* __restrict__ sorted,
                                                  const int* __restrict__ coff,
                                                  int* __restrict__ deg,
                                                  float* __restrict__ rdeg,
                                                  int N, int B, int E) {
    __shared__ int dl[BNODES];
    int b = blockIdx.x;
    int base = b << BSHIFT;
    int t = threadIdx.x;
    for (int i = t; i < BNODES; i += 256) dl[i] = 0;
    __syncthreads();
    int start = coff[b * NBLK];
    int end = (b + 1 < B) ? coff[(b + 1) * NBLK] : E;
    for (int e = start + t; e < end; e += 256)
        atomicAdd(&dl[sorted[e].y - base], 1);
    __syncthreads();
    for (int i = t; i < BNODES; i += 256) {
        int node = base + i;
        if (node < N) {
            int d = dl[i];
            deg[node] = d;
            rdeg[node] = 1.0f / (float)(d > 1 ? d : 1);
        }
    }
}

// K6: fine fill within each bucket: LDS cursors, CSR writes land in a
// contiguous ~64KB L2-resident region per bucket.
__global__ __launch_bounds__(256) void fine_fill(const int2* __restrict__ sorted,
                                                 const int* __restrict__ coff,
                                                 const int* __restrict__ row_ptr,
                                                 int* __restrict__ csr,
                                                 int N, int B, int E) {
    __shared__ int cur[BNODES];
    int b = blockIdx.x;
    int base = b << BSHIFT;
    int t = threadIdx.x;
    for (int i = t; i < BNODES; i += 256) {
        int node = base + i;
        cur[i] = (node < N) ? row_ptr[node] : 0;
    }
    __syncthreads();
    int start = coff[b * NBLK];
    int end = (b + 1 < B) ? coff[(b + 1) * NBLK] : E;
    for (int e = start + t; e < end; e += 256) {
        int2 ed = sorted[e];
        int p = atomicAdd(&cur[ed.y - base], 1);
        csr[p] = ed.x;
    }
}

// ---------------------------------------------------------------------------
// Mean aggregation: one wave (64 lanes) per dst node, float2 per lane.
// ---------------------------------------------------------------------------
__global__ __launch_bounds__(256) void agg_kernel(const float* __restrict__ h,
                                                  const int* __restrict__ row_ptr,
                                                  const int* __restrict__ deg,
                                                  const float* __restrict__ rdeg,
                                                  const int* __restrict__ csr,
                                                  float* __restrict__ out, int n) {
    int node = (blockIdx.x * 256 + threadIdx.x) >> 6;
    int lane = threadIdx.x & 63;
    if (node >= n) return;
    int start = row_ptr[node];
    int d = deg[node];
    const float2* hp = (const float2*)h;
    float ax = 0.f, ay = 0.f;
    int i = 0;
    for (; i + 4 <= d; i += 4) {
        int s0 = csr[start + i + 0];
        int s1 = csr[start + i + 1];
        int s2 = csr[start + i + 2];
        int s3 = csr[start + i + 3];
        float2 v0 = hp[s0 * 64 + lane];
        float2 v1 = hp[s1 * 64 + lane];
        float2 v2 = hp[s2 * 64 + lane];
        float2 v3 = hp[s3 * 64 + lane];
        ax += v0.x; ay += v0.y;
        ax += v1.x; ay += v1.y;
        ax += v2.x; ay += v2.y;
        ax += v3.x; ay += v3.y;
    }
    for (; i < d; ++i) {
        int s0 = csr[start + i];
        float2 v0 = hp[s0 * 64 + lane];
        ax += v0.x; ay += v0.y;
    }
    float r = rdeg[node];
    float2 o; o.x = ax * r; o.y = ay * r;
    ((float2*)out)[node * 64 + lane] = o;
}

// ---------------------------------------------------------------------------
// Fused GEMM: out[m,:] = A[m,:] @ Wl^T + H[m,:] @ Wr^T + b  (+optional ReLU)
// Block: 64 rows x 128 cols, 256 threads, each thread 8 rows x 4 cols.
// ---------------------------------------------------------------------------
__global__ __launch_bounds__(256) void gemm_kernel(const float* A, const float* H,
                                                   const float* __restrict__ Wl,
                                                   const float* __restrict__ Wr,
                                                   const float* __restrict__ bias,
                                                   float* out, int n, int do_relu) {
    __shared__ float Alds[32][64];
    __shared__ float Wlds[32][128];
    int tid = threadIdx.x;
    int block_row = blockIdx.x * 64;
    int tc = tid & 31;
    int tr = tid >> 5;

    float acc[8][4];
#pragma unroll
    for (int r = 0; r < 8; ++r)
#pragma unroll
        for (int c = 0; c < 4; ++c) acc[r][c] = 0.f;

    for (int ch = 0; ch < 8; ++ch) {
        const float* srcm = (ch < 4) ? A : H;
        const float* W    = (ch < 4) ? Wl : Wr;
        int koff = (ch & 3) * 32;

#pragma unroll
        for (int t = 0; t < 2; ++t) {
            int f4 = tid + t * 256;
            int row = f4 >> 3;
            int k4 = (f4 & 7) * 4;
            int grow = block_row + row;
            if (grow >= n) grow = n - 1;
            const float4 v = *(const float4*)(srcm + (size_t)grow * FD + koff + k4);
            Alds[k4 + 0][row] = v.x;
            Alds[k4 + 1][row] = v.y;
            Alds[k4 + 2][row] = v.z;
            Alds[k4 + 3][row] = v.w;
        }
#pragma unroll
        for (int t = 0; t < 4; ++t) {
            int f4 = tid + t * 256;
            int j = f4 >> 3;
            int k4 = (f4 & 7) * 4;
            const float4 v = *(const float4*)(W + j * FD + koff + k4);
            Wlds[k4 + 0][j] = v.x;
            Wlds[k4 + 1][j] = v.y;
            Wlds[k4 + 2][j] = v.z;
            Wlds[k4 + 3][j] = v.w;
        }
        __syncthreads();

#pragma unroll
        for (int k = 0; k < 32; ++k) {
            float4 w  = *(const float4*)&Wlds[k][tc * 4];
            float4 a0 = *(const float4*)&Alds[k][tr * 8];
            float4 a1 = *(const float4*)&Alds[k][tr * 8 + 4];
            float ar[8] = {a0.x, a0.y, a0.z, a0.w, a1.x, a1.y, a1.z, a1.w};
#pragma unroll
            for (int r = 0; r < 8; ++r) {
                acc[r][0] += ar[r] * w.x;
                acc[r][1] += ar[r] * w.y;
                acc[r][2] += ar[r] * w.z;
                acc[r][3] += ar[r] * w.w;
            }
        }
        __syncthreads();
    }

    float4 b4 = *(const float4*)(bias + tc * 4);
#pragma unroll
    for (int r = 0; r < 8; ++r) {
        int grow = block_row + tr * 8 + r;
        if (grow < n) {
            float4 o;
            o.x = acc[r][0] + b4.x;
            o.y = acc[r][1] + b4.y;
            o.z = acc[r][2] + b4.z;
            o.w = acc[r][3] + b4.w;
            if (do_relu) {
                o.x = o.x > 0.f ? o.x : 0.f;
                o.y = o.y > 0.f ? o.y : 0.f;
                o.z = o.z > 0.f ? o.z : 0.f;
                o.w = o.w > 0.f ? o.w : 0.f;
            }
            *(float4*)(out + (size_t)grow * FD + tc * 4) = o;
        }
    }
}

// ---------------------------------------------------------------------------
extern "C" void kernel_launch(void* const* d_in, const int* in_sizes, int n_in,
                              void* d_out, int out_size, void* d_ws, size_t ws_size,
                              hipStream_t stream) {
    const float* x   = (const float*)d_in[0];
    const int*   ei  = (const int*)d_in[1];
    const float* W1l = (const float*)d_in[2];
    const float* W1r = (const float*)d_in[3];
    const float* W2l = (const float*)d_in[4];
    const float* W2r = (const float*)d_in[5];
    const float* W3l = (const float*)d_in[6];
    const float* W3r = (const float*)d_in[7];
    const float* b1  = (const float*)d_in[8];
    const float* b2  = (const float*)d_in[9];
    const float* b3  = (const float*)d_in[10];
    float* out = (float*)d_out;

    int N = in_sizes[0] / FD;
    int E = in_sizes[1] / 2;
    const int* src = ei;
    const int* dst = ei + E;
    int B = (N + BNODES - 1) >> BSHIFT;          // coarse buckets (<=256)

    char* ws = (char*)d_ws;
    size_t off = 0;
    auto alloc = [&](size_t bytes) -> void* {
        void* p = ws + off;
        off += (bytes + 255) & ~(size_t)255;
        return p;
    };
    int*   deg     = (int*)alloc((size_t)N * 4);
    int*   row_ptr = (int*)alloc((size_t)N * 4);
    float* rdeg    = (float*)alloc((size_t)N * 4);
    int*   csr     = (int*)alloc((size_t)E * 4);
    int*   counts  = (int*)alloc((size_t)B * NBLK * 4);
    int*   coff    = (int*)alloc((size_t)B * NBLK * 4);
    int*   tsums   = (int*)alloc(1024 * 4);
    float* bufA    = (float*)alloc((size_t)N * FD * 4);
    float* bufB    = (float*)alloc((size_t)N * FD * 4);
    int2*  sorted  = (int2*)bufB;                // alias: sorted dead before bufB live

    // ---- CSR build via two-level counting sort ----
    int nc = B * NBLK;                           // counts length
    int ncTiles = (nc + 255) / 256;
    int ndTiles = (N + 255) / 256;

    bucket_hist<<<NBLK, 256, 0, stream>>>(dst, counts, E, B);
    scan_sums<<<ncTiles, 256, 0, stream>>>(counts, tsums, nc);
    scan_top<<<1, 1024, 0, stream>>>(tsums, ncTiles);
    scan_apply<<<ncTiles, 256, 0, stream>>>(counts, tsums, coff, nc);
    bucket_scatter<<<NBLK, 256, 0, stream>>>(src, dst, coff, sorted, E, B);
    bucket_deg<<<B, 256, 0, stream>>>(sorted, coff, deg, rdeg, N, B, E);
    scan_sums<<<ndTiles, 256, 0, stream>>>(deg, tsums, N);
    scan_top<<<1, 1024, 0, stream>>>(tsums, ndTiles);
    scan_apply<<<ndTiles, 256, 0, stream>>>(deg, tsums, row_ptr, N);
    fine_fill<<<B, 256, 0, stream>>>(sorted, coff, row_ptr, csr, N, B, E);

    int aggGrid  = (N + 3) / 4;
    int gemmGrid = (N + 63) / 64;

    // layer 1
    agg_kernel<<<aggGrid, 256, 0, stream>>>(x, row_ptr, deg, rdeg, csr, bufA, N);
    gemm_kernel<<<gemmGrid, 256, 0, stream>>>(bufA, x, W1l, W1r, b1, bufA, N, 1);
    // layer 2
    agg_kernel<<<aggGrid, 256, 0, stream>>>(bufA, row_ptr, deg, rdeg, csr, bufB, N);
    gemm_kernel<<<gemmGrid, 256, 0, stream>>>(bufB, bufA, W2l, W2r, b2, bufB, N, 1);
    // layer 3 (no relu)
    agg_kernel<<<aggGrid, 256, 0, stream>>>(bufB, row_ptr, deg, rdeg, csr, out, N);
    gemm_kernel<<<gemmGrid, 256, 0, stream>>>(out, bufB, W3l, W3r, b3, out, N, 0);
}

// Round 3
// 913.174 us; speedup vs baseline: 1.8343x; 1.2993x over previous
//
#include <hip/hip_runtime.h>

#define FD 128            // feature dim
#define NBLK 256          // blocks for bucket hist/scatter (must match grid)
#define BSHIFT 9          // bucket = dst >> 9  (512 nodes per bucket)
#define BNODES 512

// ---------------- bf16 helpers (manual, RNE pack) ----------------
__device__ __forceinline__ float bf_lo(unsigned u) { return __uint_as_float(u << 16); }
__device__ __forceinline__ float bf_hi(unsigned u) { return __uint_as_float(u & 0xffff0000u); }
__device__ __forceinline__ unsigned short bf1(float x) {
    unsigned b = __float_as_uint(x);
    return (unsigned short)((b + 0x7fffu + ((b >> 16) & 1u)) >> 16);
}
__device__ __forceinline__ unsigned bf2(float a, float b) {
    return (unsigned)bf1(a) | ((unsigned)bf1(b) << 16);
}

// ---------------------------------------------------------------------------
// fp32 -> bf16 feature conversion (x only, once per call)
// ---------------------------------------------------------------------------
__global__ __launch_bounds__(256) void to_bf16_kernel(const float4* __restrict__ in,
                                                      ushort4* __restrict__ out, int n4) {
    int i = blockIdx.x * 256 + threadIdx.x;
    if (i < n4) {
        float4 v = in[i];
        ushort4 o;
        o.x = bf1(v.x); o.y = bf1(v.y); o.z = bf1(v.z); o.w = bf1(v.w);
        out[i] = o;
    }
}

// ---------------------------------------------------------------------------
// Two-level counting sort CSR build (unchanged from R2)
// ---------------------------------------------------------------------------
__global__ __launch_bounds__(256) void bucket_hist(const int* __restrict__ dst,
                                                   int* __restrict__ counts,
                                                   int E, int B) {
    __shared__ int h[256];
    int t = threadIdx.x;
    h[t] = 0;
    __syncthreads();
    for (int e = blockIdx.x * 256 + t; e < E; e += NBLK * 256)
        atomicAdd(&h[dst[e] >> BSHIFT], 1);
    __syncthreads();
    for (int b = t; b < B; b += 256)
        counts[b * NBLK + blockIdx.x] = h[b];
}

__global__ __launch_bounds__(256) void scan_sums(const int* __restrict__ in,
                                                 int* __restrict__ sums, int n) {
    __shared__ int red[256];
    int t = threadIdx.x;
    int i = blockIdx.x * 256 + t;
    red[t] = (i < n) ? in[i] : 0;
    __syncthreads();
    for (int off = 128; off > 0; off >>= 1) {
        if (t < off) red[t] += red[t + off];
        __syncthreads();
    }
    if (t == 0) sums[blockIdx.x] = red[0];
}

__global__ __launch_bounds__(1024) void scan_top(int* __restrict__ sums, int m) {
    __shared__ int s[1024];
    int t = threadIdx.x;
    int v = (t < m) ? sums[t] : 0;
    s[t] = v;
    __syncthreads();
    for (int off = 1; off < 1024; off <<= 1) {
        int u = (t >= off) ? s[t - off] : 0;
        __syncthreads();
        s[t] += u;
        __syncthreads();
    }
    if (t < m) sums[t] = s[t] - v;   // exclusive
}

__global__ __launch_bounds__(256) void scan_apply(const int* __restrict__ in,
                                                  const int* __restrict__ sums,
                                                  int* __restrict__ out, int n) {
    __shared__ int s[256];
    int t = threadIdx.x;
    int i = blockIdx.x * 256 + t;
    int v = (i < n) ? in[i] : 0;
    s[t] = v;
    __syncthreads();
    for (int off = 1; off < 256; off <<= 1) {
        int u = (t >= off) ? s[t - off] : 0;
        __syncthreads();
        s[t] += u;
        __syncthreads();
    }
    if (i < n) out[i] = sums[blockIdx.x] + s[t] - v;   // exclusive
}

__global__ __launch_bounds__(256) void bucket_scatter(const int* __restrict__ src,
                                                      const int* __restrict__ dst,
                                                      const int* __restrict__ coff,
                                                      int2* __restrict__ sorted,
                                                      int E, int B) {
    __shared__ int cur[256];
    int t = threadIdx.x;
    for (int b = t; b < B; b += 256) cur[b] = coff[b * NBLK + blockIdx.x];
    __syncthreads();
    for (int e = blockIdx.x * 256 + t; e < E; e += NBLK * 256) {
        int d = dst[e];
        int p = atomicAdd(&cur[d >> BSHIFT], 1);
        sorted[p] = make_int2(src[e], d);
    }
}

__global__ __launch_bounds__(256) void bucket_deg(const int2* __restrict__ sorted,
                                                  const int* __restrict__ coff,
                                                  int* __restrict__ deg,
                                                  float* __restrict__ rdeg,
                                                  int N, int B, int E) {
    __shared__ int dl[BNODES];
    int b = blockIdx.x;
    int base = b << BSHIFT;
    int t = threadIdx.x;
    for (int i = t; i < BNODES; i += 256) dl[i] = 0;
    __syncthreads();
    int start = coff[b * NBLK];
    int end = (b + 1 < B) ? coff[(b + 1) * NBLK] : E;
    for (int e = start + t; e < end; e += 256)
        atomicAdd(&dl[sorted[e].y - base], 1);
    __syncthreads();
    for (int i = t; i < BNODES; i += 256) {
        int node = base + i;
        if (node < N) {
            int d = dl[i];
            deg[node] = d;
            rdeg[node] = 1.0f / (float)(d > 1 ? d : 1);
        }
    }
}

__global__ __launch_bounds__(256) void fine_fill(const int2* __restrict__ sorted,
                                                 const int* __restrict__ coff,
                                                 const int* __restrict__ row_ptr,
                                                 int* __restrict__ csr,
                                                 int N, int B, int E) {
    __shared__ int cur[BNODES];
    int b = blockIdx.x;
    int base = b << BSHIFT;
    int t = threadIdx.x;
    for (int i = t; i < BNODES; i += 256) {
        int node = base + i;
        cur[i] = (node < N) ? row_ptr[node] : 0;
    }
    __syncthreads();
    int start = coff[b * NBLK];
    int end = (b + 1 < B) ? coff[(b + 1) * NBLK] : E;
    for (int e = start + t; e < end; e += 256) {
        int2 ed = sorted[e];
        int p = atomicAdd(&cur[ed.y - base], 1);
        csr[p] = ed.x;
    }
}

// ---------------------------------------------------------------------------
// Mean aggregation over bf16 features: one wave per dst node, 1 uint
// (2 bf16 cols) per lane -> 256 B per row request, fp32 accumulate,
// bf16 (RNE) output.
// ---------------------------------------------------------------------------
__global__ __launch_bounds__(256) void agg_kernel(const unsigned* __restrict__ h,   // N x 64 uints
                                                  const int* __restrict__ row_ptr,
                                                  const int* __restrict__ deg,
                                                  const float* __restrict__ rdeg,
                                                  const int* __restrict__ csr,
                                                  unsigned* __restrict__ out, int n) {
    int node = (blockIdx.x * 256 + threadIdx.x) >> 6;
    int lane = threadIdx.x & 63;
    if (node >= n) return;
    int start = row_ptr[node];
    int d = deg[node];
    float ax = 0.f, ay = 0.f;
    int i = 0;
    for (; i + 4 <= d; i += 4) {
        int s0 = csr[start + i + 0];
        int s1 = csr[start + i + 1];
        int s2 = csr[start + i + 2];
        int s3 = csr[start + i + 3];
        unsigned v0 = h[s0 * 64 + lane];
        unsigned v1 = h[s1 * 64 + lane];
        unsigned v2 = h[s2 * 64 + lane];
        unsigned v3 = h[s3 * 64 + lane];
        ax += bf_lo(v0); ay += bf_hi(v0);
        ax += bf_lo(v1); ay += bf_hi(v1);
        ax += bf_lo(v2); ay += bf_hi(v2);
        ax += bf_lo(v3); ay += bf_hi(v3);
    }
    for (; i < d; ++i) {
        unsigned v0 = h[csr[start + i] * 64 + lane];
        ax += bf_lo(v0); ay += bf_hi(v0);
    }
    float r = rdeg[node];
    out[node * 64 + lane] = bf2(ax * r, ay * r);
}

// ---------------------------------------------------------------------------
// Fused GEMM: out[m,:] = A[m,:] @ Wl^T + H[m,:] @ Wr^T + b  (+optional ReLU)
// A, H are bf16 (N x 128); W, bias fp32; LDS + accumulate fp32 (inner loop
// identical to R2 — bf16->fp32 conversion happens during staging).
// OUT_FP32=0: write bf16 feature buffer; OUT_FP32=1: write fp32 d_out.
// ---------------------------------------------------------------------------
template <int OUT_FP32>
__global__ __launch_bounds__(256) void gemm_kernel(const unsigned short* A,
                                                   const unsigned short* H,
                                                   const float* __restrict__ Wl,
                                                   const float* __restrict__ Wr,
                                                   const float* __restrict__ bias,
                                                   void* outp, int n, int do_relu) {
    __shared__ float Alds[32][64];
    __shared__ float Wlds[32][128];
    int tid = threadIdx.x;
    int block_row = blockIdx.x * 64;
    int tc = tid & 31;
    int tr = tid >> 5;

    float acc[8][4];
#pragma unroll
    for (int r = 0; r < 8; ++r)
#pragma unroll
        for (int c = 0; c < 4; ++c) acc[r][c] = 0.f;

    for (int ch = 0; ch < 8; ++ch) {
        const unsigned short* srcm = (ch < 4) ? A : H;
        const float* W = (ch < 4) ? Wl : Wr;
        int koff = (ch & 3) * 32;

        // stage A tile (64 rows x 32 k, bf16) transposed -> Alds[k][row], fp32
        {
            int row = tid >> 2;
            int k8 = (tid & 3) * 8;
            int grow = block_row + row;
            if (grow >= n) grow = n - 1;
            const uint4 v = *(const uint4*)(srcm + (size_t)grow * FD + koff + k8);
            Alds[k8 + 0][row] = bf_lo(v.x);
            Alds[k8 + 1][row] = bf_hi(v.x);
            Alds[k8 + 2][row] = bf_lo(v.y);
            Alds[k8 + 3][row] = bf_hi(v.y);
            Alds[k8 + 4][row] = bf_lo(v.z);
            Alds[k8 + 5][row] = bf_hi(v.z);
            Alds[k8 + 6][row] = bf_lo(v.w);
            Alds[k8 + 7][row] = bf_hi(v.w);
        }
        // stage W tile (128 j x 32 k, fp32) transposed -> Wlds[k][j]
#pragma unroll
        for (int t = 0; t < 4; ++t) {
            int f4 = tid + t * 256;
            int j = f4 >> 3;
            int k4 = (f4 & 7) * 4;
            const float4 v = *(const float4*)(W + j * FD + koff + k4);
            Wlds[k4 + 0][j] = v.x;
            Wlds[k4 + 1][j] = v.y;
            Wlds[k4 + 2][j] = v.z;
            Wlds[k4 + 3][j] = v.w;
        }
        __syncthreads();

#pragma unroll
        for (int k = 0; k < 32; ++k) {
            float4 w  = *(const float4*)&Wlds[k][tc * 4];
            float4 a0 = *(const float4*)&Alds[k][tr * 8];
            float4 a1 = *(const float4*)&Alds[k][tr * 8 + 4];
            float ar[8] = {a0.x, a0.y, a0.z, a0.w, a1.x, a1.y, a1.z, a1.w};
#pragma unroll
            for (int r = 0; r < 8; ++r) {
                acc[r][0] += ar[r] * w.x;
                acc[r][1] += ar[r] * w.y;
                acc[r][2] += ar[r] * w.z;
                acc[r][3] += ar[r] * w.w;
            }
        }
        __syncthreads();
    }

    float4 b4 = *(const float4*)(bias + tc * 4);
#pragma unroll
    for (int r = 0; r < 8; ++r) {
        int grow = block_row + tr * 8 + r;
        if (grow < n) {
            float4 o;
            o.x = acc[r][0] + b4.x;
            o.y = acc[r][1] + b4.y;
            o.z = acc[r][2] + b4.z;
            o.w = acc[r][3] + b4.w;
            if (do_relu) {
                o.x = o.x > 0.f ? o.x : 0.f;
                o.y = o.y > 0.f ? o.y : 0.f;
                o.z = o.z > 0.f ? o.z : 0.f;
                o.w = o.w > 0.f ? o.w : 0.f;
            }
            if (OUT_FP32) {
                *(float4*)((float*)outp + (size_t)grow * FD + tc * 4) = o;
            } else {
                ushort4 ob;
                ob.x = bf1(o.x); ob.y = bf1(o.y); ob.z = bf1(o.z); ob.w = bf1(o.w);
                *(ushort4*)((unsigned short*)outp + (size_t)grow * FD + tc * 4) = ob;
            }
        }
    }
}

// ---------------------------------------------------------------------------
extern "C" void kernel_launch(void* const* d_in, const int* in_sizes, int n_in,
                              void* d_out, int out_size, void* d_ws, size_t ws_size,
                              hipStream_t stream) {
    const float* x   = (const float*)d_in[0];
    const int*   ei  = (const int*)d_in[1];
    const float* W1l = (const float*)d_in[2];
    const float* W1r = (const float*)d_in[3];
    const float* W2l = (const float*)d_in[4];
    const float* W2r = (const float*)d_in[5];
    const float* W3l = (const float*)d_in[6];
    const float* W3r = (const float*)d_in[7];
    const float* b1  = (const float*)d_in[8];
    const float* b2  = (const float*)d_in[9];
    const float* b3  = (const float*)d_in[10];
    float* out = (float*)d_out;

    int N = in_sizes[0] / FD;
    int E = in_sizes[1] / 2;
    const int* src = ei;
    const int* dst = ei + E;
    int B = (N + BNODES - 1) >> BSHIFT;

    char* ws = (char*)d_ws;
    size_t off = 0;
    auto alloc = [&](size_t bytes) -> void* {
        void* p = ws + off;
        off += (bytes + 255) & ~(size_t)255;
        return p;
    };
    int*            deg     = (int*)alloc((size_t)N * 4);
    int*            row_ptr = (int*)alloc((size_t)N * 4);
    float*          rdeg    = (float*)alloc((size_t)N * 4);
    int*            csr     = (int*)alloc((size_t)E * 4);
    int*            counts  = (int*)alloc((size_t)B * NBLK * 4);
    int*            coff    = (int*)alloc((size_t)B * NBLK * 4);
    int*            tsums   = (int*)alloc(1024 * 4);
    unsigned short* xb      = (unsigned short*)alloc((size_t)N * FD * 2);
    unsigned short* h1      = (unsigned short*)alloc((size_t)N * FD * 2);
    unsigned short* h2      = (unsigned short*)alloc((size_t)N * FD * 2);
    unsigned short* aggB    = (unsigned short*)alloc((size_t)N * FD * 2);
    int2* sorted = (int2*)h2;   // alias: sorted dead (after fine_fill) before h2 live (gemm2)

    // ---- x -> bf16 ----
    int n4 = N * FD / 4;
    to_bf16_kernel<<<(n4 + 255) / 256, 256, 0, stream>>>((const float4*)x, (ushort4*)xb, n4);

    // ---- CSR build via two-level counting sort ----
    int nc = B * NBLK;
    int ncTiles = (nc + 255) / 256;
    int ndTiles = (N + 255) / 256;

    bucket_hist<<<NBLK, 256, 0, stream>>>(dst, counts, E, B);
    scan_sums<<<ncTiles, 256, 0, stream>>>(counts, tsums, nc);
    scan_top<<<1, 1024, 0, stream>>>(tsums, ncTiles);
    scan_apply<<<ncTiles, 256, 0, stream>>>(counts, tsums, coff, nc);
    bucket_scatter<<<NBLK, 256, 0, stream>>>(src, dst, coff, sorted, E, B);
    bucket_deg<<<B, 256, 0, stream>>>(sorted, coff, deg, rdeg, N, B, E);
    scan_sums<<<ndTiles, 256, 0, stream>>>(deg, tsums, N);
    scan_top<<<1, 1024, 0, stream>>>(tsums, ndTiles);
    scan_apply<<<ndTiles, 256, 0, stream>>>(deg, tsums, row_ptr, N);
    fine_fill<<<B, 256, 0, stream>>>(sorted, coff, row_ptr, csr, N, B, E);

    int aggGrid  = (N + 3) / 4;
    int gemmGrid = (N + 63) / 64;

    // layer 1
    agg_kernel<<<aggGrid, 256, 0, stream>>>((const unsigned*)xb, row_ptr, deg, rdeg, csr,
                                            (unsigned*)aggB, N);
    gemm_kernel<0><<<gemmGrid, 256, 0, stream>>>(aggB, xb, W1l, W1r, b1, h1, N, 1);
    // layer 2
    agg_kernel<<<aggGrid, 256, 0, stream>>>((const unsigned*)h1, row_ptr, deg, rdeg, csr,
                                            (unsigned*)aggB, N);
    gemm_kernel<0><<<gemmGrid, 256, 0, stream>>>(aggB, h1, W2l, W2r, b2, h2, N, 1);
    // layer 3 (no relu, fp32 out)
    agg_kernel<<<aggGrid, 256, 0, stream>>>((const unsigned*)h2, row_ptr, deg, rdeg, csr,
                                            (unsigned*)aggB, N);
    gemm_kernel<1><<<gemmGrid, 256, 0, stream>>>(aggB, h2, W3l, W3r, b3, out, N, 0);
}

// Round 4
// 780.284 us; speedup vs baseline: 2.1467x; 1.1703x over previous
//
#include <hip/hip_runtime.h>
#include <hip/hip_fp16.h>

#define FD 128            // feature dim
#define NBLK 256          // blocks for bucket hist/scatter (must match grid)
#define BSHIFT 9          // bucket = dst >> 9  (512 nodes per bucket)
#define BNODES 512

typedef _Float16 half8 __attribute__((ext_vector_type(8)));
typedef float floatx4 __attribute__((ext_vector_type(4)));

// ---------------------------------------------------------------------------
// fp32 -> f16 feature conversion (x only, once per call)
// ---------------------------------------------------------------------------
__global__ __launch_bounds__(256) void to_f16_kernel(const float4* __restrict__ in,
                                                     __half2* __restrict__ out, int n4) {
    int i = blockIdx.x * 256 + threadIdx.x;
    if (i < n4) {
        float4 v = in[i];
        out[2 * i + 0] = __floats2half2_rn(v.x, v.y);
        out[2 * i + 1] = __floats2half2_rn(v.z, v.w);
    }
}

// ---------------------------------------------------------------------------
// Pack one layer's [Wl;Wr] (each 128x128 fp32, row-major [n][k]) into MFMA
// B-fragment order (f16): frag_idx = (nt*8 + kt)*64 + lane, 8 f16 each.
// B[k][n] with n = nt*16 + (lane&15), k = kt*32 + (lane>>4)*8 + j.
// ---------------------------------------------------------------------------
__global__ __launch_bounds__(256) void pack_w_kernel(const float* __restrict__ Wl,
                                                     const float* __restrict__ Wr,
                                                     half8* __restrict__ out) {
    int t = blockIdx.x * 256 + threadIdx.x;   // 0..4095
    int lane = t & 63;
    int kt = (t >> 6) & 7;
    int nt = t >> 9;
    int n = nt * 16 + (lane & 15);
    int kq = kt * 32 + ((lane >> 4) & 3) * 8;
    half8 f;
#pragma unroll
    for (int j = 0; j < 8; ++j) {
        int k = kq + j;
        float v = (k < 128) ? Wl[n * 128 + k] : Wr[n * 128 + (k - 128)];
        f[j] = (_Float16)v;
    }
    out[t] = f;
}

// ---------------------------------------------------------------------------
// Two-level counting sort CSR build (unchanged)
// ---------------------------------------------------------------------------
__global__ __launch_bounds__(256) void bucket_hist(const int* __restrict__ dst,
                                                   int* __restrict__ counts,
                                                   int E, int B) {
    __shared__ int h[256];
    int t = threadIdx.x;
    h[t] = 0;
    __syncthreads();
    for (int e = blockIdx.x * 256 + t; e < E; e += NBLK * 256)
        atomicAdd(&h[dst[e] >> BSHIFT], 1);
    __syncthreads();
    for (int b = t; b < B; b += 256)
        counts[b * NBLK + blockIdx.x] = h[b];
}

__global__ __launch_bounds__(256) void scan_sums(const int* __restrict__ in,
                                                 int* __restrict__ sums, int n) {
    __shared__ int red[256];
    int t = threadIdx.x;
    int i = blockIdx.x * 256 + t;
    red[t] = (i < n) ? in[i] : 0;
    __syncthreads();
    for (int off = 128; off > 0; off >>= 1) {
        if (t < off) red[t] += red[t + off];
        __syncthreads();
    }
    if (t == 0) sums[blockIdx.x] = red[0];
}

__global__ __launch_bounds__(1024) void scan_top(int* __restrict__ sums, int m) {
    __shared__ int s[1024];
    int t = threadIdx.x;
    int v = (t < m) ? sums[t] : 0;
    s[t] = v;
    __syncthreads();
    for (int off = 1; off < 1024; off <<= 1) {
        int u = (t >= off) ? s[t - off] : 0;
        __syncthreads();
        s[t] += u;
        __syncthreads();
    }
    if (t < m) sums[t] = s[t] - v;   // exclusive
}

__global__ __launch_bounds__(256) void scan_apply(const int* __restrict__ in,
                                                  const int* __restrict__ sums,
                                                  int* __restrict__ out, int n) {
    __shared__ int s[256];
    int t = threadIdx.x;
    int i = blockIdx.x * 256 + t;
    int v = (i < n) ? in[i] : 0;
    s[t] = v;
    __syncthreads();
    for (int off = 1; off < 256; off <<= 1) {
        int u = (t >= off) ? s[t - off] : 0;
        __syncthreads();
        s[t] += u;
        __syncthreads();
    }
    if (i < n) out[i] = sums[blockIdx.x] + s[t] - v;   // exclusive
}

__global__ __launch_bounds__(256) void bucket_scatter(const int* __restrict__ src,
                                                      const int* __restrict__ dst,
                                                      const int* __restrict__ coff,
                                                      int2* __restrict__ sorted,
                                                      int E, int B) {
    __shared__ int cur[256];
    int t = threadIdx.x;
    for (int b = t; b < B; b += 256) cur[b] = coff[b * NBLK + blockIdx.x];
    __syncthreads();
    for (int e = blockIdx.x * 256 + t; e < E; e += NBLK * 256) {
        int d = dst[e];
        int p = atomicAdd(&cur[d >> BSHIFT], 1);
        sorted[p] = make_int2(src[e], d);
    }
}

__global__ __launch_bounds__(256) void bucket_deg(const int2* __restrict__ sorted,
                                                  const int* __restrict__ coff,
                                                  int* __restrict__ deg,
                                                  float* __restrict__ rdeg,
                                                  int N, int B, int E) {
    __shared__ int dl[BNODES];
    int b = blockIdx.x;
    int base = b << BSHIFT;
    int t = threadIdx.x;
    for (int i = t; i < BNODES; i += 256) dl[i] = 0;
    __syncthreads();
    int start = coff[b * NBLK];
    int end = (b + 1 < B) ? coff[(b + 1) * NBLK] : E;
    for (int e = start + t; e < end; e += 256)
        atomicAdd(&dl[sorted[e].y - base], 1);
    __syncthreads();
    for (int i = t; i < BNODES; i += 256) {
        int node = base + i;
        if (node < N) {
            int d = dl[i];
            deg[node] = d;
            rdeg[node] = 1.0f / (float)(d > 1 ? d : 1);
        }
    }
}

__global__ __launch_bounds__(256) void fine_fill(const int2* __restrict__ sorted,
                                                 const int* __restrict__ coff,
                                                 const int* __restrict__ row_ptr,
                                                 int* __restrict__ csr,
                                                 int N, int B, int E) {
    __shared__ int cur[BNODES];
    int b = blockIdx.x;
    int base = b << BSHIFT;
    int t = threadIdx.x;
    for (int i = t; i < BNODES; i += 256) {
        int node = base + i;
        cur[i] = (node < N) ? row_ptr[node] : 0;
    }
    __syncthreads();
    int start = coff[b * NBLK];
    int end = (b + 1 < B) ? coff[(b + 1) * NBLK] : E;
    for (int e = start + t; e < end; e += 256) {
        int2 ed = sorted[e];
        int p = atomicAdd(&cur[ed.y - base], 1);
        csr[p] = ed.x;
    }
}

// ---------------------------------------------------------------------------
// Mean aggregation over f16 features: one wave per dst node, 1 half2
// (2 cols) per lane, fp32 accumulate, f16 RNE output.
// ---------------------------------------------------------------------------
__global__ __launch_bounds__(256) void agg_kernel(const __half2* __restrict__ h,  // N x 64 half2
                                                  const int* __restrict__ row_ptr,
                                                  const int* __restrict__ deg,
                                                  const float* __restrict__ rdeg,
                                                  const int* __restrict__ csr,
                                                  __half2* __restrict__ out, int n) {
    int node = (blockIdx.x * 256 + threadIdx.x) >> 6;
    int lane = threadIdx.x & 63;
    if (node >= n) return;
    int start = row_ptr[node];
    int d = deg[node];
    float ax = 0.f, ay = 0.f;
    int i = 0;
    for (; i + 4 <= d; i += 4) {
        int s0 = csr[start + i + 0];
        int s1 = csr[start + i + 1];
        int s2 = csr[start + i + 2];
        int s3 = csr[start + i + 3];
        float2 v0 = __half22float2(h[s0 * 64 + lane]);
        float2 v1 = __half22float2(h[s1 * 64 + lane]);
        float2 v2 = __half22float2(h[s2 * 64 + lane]);
        float2 v3 = __half22float2(h[s3 * 64 + lane]);
        ax += v0.x; ay += v0.y;
        ax += v1.x; ay += v1.y;
        ax += v2.x; ay += v2.y;
        ax += v3.x; ay += v3.y;
    }
    for (; i < d; ++i) {
        float2 v0 = __half22float2(h[csr[start + i] * 64 + lane]);
        ax += v0.x; ay += v0.y;
    }
    float r = rdeg[node];
    out[node * 64 + lane] = __floats2half2_rn(ax * r, ay * r);
}

// ---------------------------------------------------------------------------
// MFMA GEMM: out[m,:] = cat(A,H)[m,:] @ Wcat^T + b  (+optional ReLU)
// A, H: N x 128 f16. Wfrag: fragment-packed f16 weights (B-operand order).
// Block = 256 thr = 4 waves; 128 rows x 128 cols per block; wave w covers
// rows w*32..w*32+31 (2 m-tiles of 16). No LDS, no barriers.
// mfma_f32_16x16x32_f16 layouts (guide §3, m89/m120 verified):
//   A[m=lane&15][k=quad*8+j], B[k=quad*8+j][n=lane&15],
//   C/D: col=lane&15, row=quad*4+reg.
// ---------------------------------------------------------------------------
template <int OUT_FP32>
__global__ __launch_bounds__(256) void gemm_mfma(const __half* __restrict__ A,
                                                 const __half* __restrict__ H,
                                                 const half8* __restrict__ Wfrag,
                                                 const float* __restrict__ bias,
                                                 void* outp, int n, int do_relu) {
    int tid = threadIdx.x;
    int wave = tid >> 6;
    int lane = tid & 63;
    int quad = (lane >> 4) & 3;
    int l16 = lane & 15;
    long tilebase = (long)blockIdx.x * 128;
    long r0 = tilebase + wave * 32 + l16;      // A row, m-tile 0
    long r1 = r0 + 16;                         // A row, m-tile 1
    long ra = (r0 < n) ? r0 : (n - 1);
    long rb = (r1 < n) ? r1 : (n - 1);

    floatx4 acc[2][8];
#pragma unroll
    for (int m = 0; m < 2; ++m)
#pragma unroll
        for (int nt = 0; nt < 8; ++nt) acc[m][nt] = (floatx4){0.f, 0.f, 0.f, 0.f};

#pragma unroll
    for (int kt = 0; kt < 8; ++kt) {
        const __half* src = (kt < 4) ? A : H;
        int koff = (kt & 3) * 32 + quad * 8;          // col within 128-wide row
        half8 a0 = *(const half8*)(src + (size_t)ra * FD + koff);
        half8 a1 = *(const half8*)(src + (size_t)rb * FD + koff);
#pragma unroll
        for (int nt = 0; nt < 8; ++nt) {
            half8 b = Wfrag[(size_t)(nt * 8 + kt) * 64 + lane];
            acc[0][nt] = __builtin_amdgcn_mfma_f32_16x16x32_f16(a0, b, acc[0][nt], 0, 0, 0);
            acc[1][nt] = __builtin_amdgcn_mfma_f32_16x16x32_f16(a1, b, acc[1][nt], 0, 0, 0);
        }
    }

#pragma unroll
    for (int m = 0; m < 2; ++m) {
#pragma unroll
        for (int nt = 0; nt < 8; ++nt) {
            int col = nt * 16 + l16;
            float bv = bias[col];
#pragma unroll
            for (int r = 0; r < 4; ++r) {
                long row = tilebase + wave * 32 + m * 16 + quad * 4 + r;
                if (row < n) {
                    float v = acc[m][nt][r] + bv;
                    if (do_relu) v = v > 0.f ? v : 0.f;
                    if (OUT_FP32)
                        ((float*)outp)[row * FD + col] = v;
                    else
                        ((__half*)outp)[row * FD + col] = __float2half_rn(v);
                }
            }
        }
    }
}

// ---------------------------------------------------------------------------
extern "C" void kernel_launch(void* const* d_in, const int* in_sizes, int n_in,
                              void* d_out, int out_size, void* d_ws, size_t ws_size,
                              hipStream_t stream) {
    const float* x   = (const float*)d_in[0];
    const int*   ei  = (const int*)d_in[1];
    const float* W1l = (const float*)d_in[2];
    const float* W1r = (const float*)d_in[3];
    const float* W2l = (const float*)d_in[4];
    const float* W2r = (const float*)d_in[5];
    const float* W3l = (const float*)d_in[6];
    const float* W3r = (const float*)d_in[7];
    const float* b1  = (const float*)d_in[8];
    const float* b2  = (const float*)d_in[9];
    const float* b3  = (const float*)d_in[10];
    float* out = (float*)d_out;

    int N = in_sizes[0] / FD;
    int E = in_sizes[1] / 2;
    const int* src = ei;
    const int* dst = ei + E;
    int B = (N + BNODES - 1) >> BSHIFT;

    char* ws = (char*)d_ws;
    size_t off = 0;
    auto alloc = [&](size_t bytes) -> void* {
        void* p = ws + off;
        off += (bytes + 255) & ~(size_t)255;
        return p;
    };
    int*    deg     = (int*)alloc((size_t)N * 4);
    int*    row_ptr = (int*)alloc((size_t)N * 4);
    float*  rdeg    = (float*)alloc((size_t)N * 4);
    int*    csr     = (int*)alloc((size_t)E * 4);
    int*    counts  = (int*)alloc((size_t)B * NBLK * 4);
    int*    coff    = (int*)alloc((size_t)B * NBLK * 4);
    int*    tsums   = (int*)alloc(1024 * 4);
    __half* xb      = (__half*)alloc((size_t)N * FD * 2);
    __half* h1      = (__half*)alloc((size_t)N * FD * 2);
    __half* h2      = (__half*)alloc((size_t)N * FD * 2);
    __half* aggB    = (__half*)alloc((size_t)N * FD * 2);
    half8*  wf1     = (half8*)alloc(4096 * 16);
    half8*  wf2     = (half8*)alloc(4096 * 16);
    half8*  wf3     = (half8*)alloc(4096 * 16);
    int2* sorted = (int2*)h2;   // alias: sorted dead (after fine_fill) before h2 live

    // ---- conversions / weight packing ----
    int n4 = N * FD / 4;
    to_f16_kernel<<<(n4 + 255) / 256, 256, 0, stream>>>((const float4*)x, (__half2*)xb, n4);
    pack_w_kernel<<<16, 256, 0, stream>>>(W1l, W1r, wf1);
    pack_w_kernel<<<16, 256, 0, stream>>>(W2l, W2r, wf2);
    pack_w_kernel<<<16, 256, 0, stream>>>(W3l, W3r, wf3);

    // ---- CSR build via two-level counting sort ----
    int nc = B * NBLK;
    int ncTiles = (nc + 255) / 256;
    int ndTiles = (N + 255) / 256;

    bucket_hist<<<NBLK, 256, 0, stream>>>(dst, counts, E, B);
    scan_sums<<<ncTiles, 256, 0, stream>>>(counts, tsums, nc);
    scan_top<<<1, 1024, 0, stream>>>(tsums, ncTiles);
    scan_apply<<<ncTiles, 256, 0, stream>>>(counts, tsums, coff, nc);
    bucket_scatter<<<NBLK, 256, 0, stream>>>(src, dst, coff, sorted, E, B);
    bucket_deg<<<B, 256, 0, stream>>>(sorted, coff, deg, rdeg, N, B, E);
    scan_sums<<<ndTiles, 256, 0, stream>>>(deg, tsums, N);
    scan_top<<<1, 1024, 0, stream>>>(tsums, ndTiles);
    scan_apply<<<ndTiles, 256, 0, stream>>>(deg, tsums, row_ptr, N);
    fine_fill<<<B, 256, 0, stream>>>(sorted, coff, row_ptr, csr, N, B, E);

    int aggGrid  = (N + 3) / 4;
    int gemmGrid = (N + 127) / 128;

    // layer 1
    agg_kernel<<<aggGrid, 256, 0, stream>>>((const __half2*)xb, row_ptr, deg, rdeg, csr,
                                            (__half2*)aggB, N);
    gemm_mfma<0><<<gemmGrid, 256, 0, stream>>>(aggB, xb, wf1, b1, h1, N, 1);
    // layer 2
    agg_kernel<<<aggGrid, 256, 0, stream>>>((const __half2*)h1, row_ptr, deg, rdeg, csr,
                                            (__half2*)aggB, N);
    gemm_mfma<0><<<gemmGrid, 256, 0, stream>>>(aggB, h1, wf2, b2, h2, N, 1);
    // layer 3 (no relu, fp32 out)
    agg_kernel<<<aggGrid, 256, 0, stream>>>((const __half2*)h2, row_ptr, deg, rdeg, csr,
                                            (__half2*)aggB, N);
    gemm_mfma<1><<<gemmGrid, 256, 0, stream>>>(aggB, h2, wf3, b3, out, N, 0);
}